// Round 9
// baseline (213.706 us; speedup 1.0000x reference)
//
#include <hip/hip_runtime.h>

#define NEG_INF (-3.402823466e+38f)  // -FLT_MAX

// DPP helper (float through int). CTRL = DPP control word.
template <int CTRL>
__device__ __forceinline__ float dppf(float v) {
    return __int_as_float(__builtin_amdgcn_update_dpp(
        __float_as_int(v), __float_as_int(v), CTRL, 0xF, 0xF, false));
}

// max with DPP row-rotate; direction-agnostic (used for reductions only)
template <int CTRL>
__device__ __forceinline__ float rormax(float v) {
    return fmaxf(v, dppf<CTRL>(v));
}

// Insert v into sorted-descending top-12 L. new L[j] = med3(v, L[j-1], L[j]).
__device__ __forceinline__ void insert12(float L[12], const float v) {
    const float p0 = L[0], p1 = L[1], p2 = L[2], p3 = L[3], p4 = L[4],
                p5 = L[5], p6 = L[6], p7 = L[7], p8 = L[8], p9 = L[9],
                p10 = L[10];
    L[0] = fmaxf(p0, v);
    L[1] = __builtin_amdgcn_fmed3f(v, p0, p1);
    L[2] = __builtin_amdgcn_fmed3f(v, p1, p2);
    L[3] = __builtin_amdgcn_fmed3f(v, p2, p3);
    L[4] = __builtin_amdgcn_fmed3f(v, p3, p4);
    L[5] = __builtin_amdgcn_fmed3f(v, p4, p5);
    L[6] = __builtin_amdgcn_fmed3f(v, p5, p6);
    L[7] = __builtin_amdgcn_fmed3f(v, p6, p7);
    L[8] = __builtin_amdgcn_fmed3f(v, p7, p8);
    L[9] = __builtin_amdgcn_fmed3f(v, p8, p9);
    L[10] = __builtin_amdgcn_fmed3f(v, p9, p10);
    L[11] = __builtin_amdgcn_fmed3f(v, p10, L[11]);
}

// One chunk: 16 lanes x float4 = 64 consecutive elements of one row.
// Lane h holds elements 4h..4h+3 (of the chunk). prev-3 come from lane h-1
// via DPP rotate (CTRL = ror:1 or its mirror), h==0 uses the inter-chunk
// carry (= previous chunk's DPP result captured at lane 0).
// MODE: 0 = first chunk (mask e<3), 1 = mid, 2 = tail (lanes h>=10 invalid).
template <int CTRL, int MODE>
__device__ __forceinline__ void chunkproc(const float4 a, const int h,
                                          float& cy, float& cz, float& cw,
                                          float L[12]) {
    const float dy = dppf<CTRL>(a.y);
    const float dz = dppf<CTRL>(a.z);
    const float dw = dppf<CTRL>(a.w);
    const bool h0 = (h == 0);
    const float p3 = h0 ? cy : dy;  // element e0-3
    const float p2 = h0 ? cz : dz;  // element e0-2
    const float p1 = h0 ? cw : dw;  // element e0-1
    float w0 = a.x + p1 + p2 + p3;
    float w1 = w0 + a.y - p3;
    float w2 = w1 + a.z - p2;
    float w3 = w2 + a.w - p1;
    if (MODE == 0) {  // windows ending at e=0,1,2 don't exist (lane 0 only)
        w0 = h0 ? NEG_INF : w0;
        w1 = h0 ? NEG_INF : w1;
        w2 = h0 ? NEG_INF : w2;
    }
    if (MODE == 2) {  // tail chunk: cols 240+h valid only for h<=9
        const bool inv = (h >= 10);
        w0 = inv ? NEG_INF : w0;
        w1 = inv ? NEG_INF : w1;
        w2 = inv ? NEG_INF : w2;
        w3 = inv ? NEG_INF : w3;
    }
    cy = dy; cz = dz; cw = dw;  // lane 0 captures lane 15's values for next chunk
    insert12(L, w0);
    insert12(L, w1);
    insert12(L, w2);
    insert12(L, w3);
}

// Process one row (1000 elements) spread over a 16-lane group; returns the
// sum of its top-12 window sums (uniform across the 16 lanes).
template <int CTRL>
__device__ __forceinline__ float do_row(const float4* __restrict__ pr, const int l) {
    const int h = l & 15;
    float L[12];
#pragma unroll
    for (int j = 0; j < 12; ++j) L[j] = NEG_INF;
    float cy = 0.f, cz = 0.f, cw = 0.f;

    // chunk s covers elements 64s..64s+63 (cols 16s..16s+15); 15 full + tail
    float4 a = pr[h];         // chunk 0
    float4 b = pr[16 + h];    // chunk 1
    {
        float4 nb = pr[32 + h];                 // chunk 2
        chunkproc<CTRL, 0>(a, h, cy, cz, cw, L);
        a = b; b = nb;
    }
#pragma unroll 2
    for (int s = 1; s <= 13; ++s) {
        int c = (s + 2) * 16 + h;               // chunk s+2; clamp for tail
        c = c < 249 ? c : 249;
        float4 nb = pr[c];
        chunkproc<CTRL, 1>(a, h, cy, cz, cw, L);
        a = b; b = nb;
    }
    chunkproc<CTRL, 1>(a, h, cy, cz, cw, L);    // chunk 14 (elements 896..959)
    chunkproc<CTRL, 2>(b, h, cy, cz, cw, L);    // chunk 15 (960..999 + masked)

    // merge 16 sorted-12 lists: 12 rounds of within-16 max-extraction
    float s12 = 0.f;
#pragma unroll
    for (int rd = 0; rd < 12; ++rd) {
        const float hd = L[0];
        float g = rormax<0x121>(hd);   // ror:1
        g = rormax<0x122>(g);          // ror:2
        g = rormax<0x124>(g);          // ror:4
        g = rormax<0x128>(g);          // ror:8 -> 16-lane-group max, all lanes
        s12 += g;
        const unsigned long long ball = __ballot(hd == g);
        const unsigned grp = (unsigned)((ball >> (l & ~15)) & 0xFFFFu);
        const bool pop = (h == (int)__builtin_ctz(grp));  // unique winner
#pragma unroll
        for (int i = 0; i < 11; ++i) L[i] = pop ? L[i + 1] : L[i];
        L[11] = pop ? NEG_INF : L[11];
    }
    return s12;
}

// 16 lanes per row -> 256 B contiguous per row per load instruction, 4 rows
// per wave (sequential groups of 4): 128 concurrent row-streams/CU vs R8's
// 512. Block = 512 threads = 8 waves x 16 rows = 128 rows = 1 output.
__global__ __launch_bounds__(512) void ssrp_hex_kernel(const float* __restrict__ x,
                                                       float* __restrict__ out) {
    __shared__ float wsum[8];
    const int t = threadIdx.x;
    const int wv = t >> 6;
    const int l = t & 63;
    const int r = l >> 4;  // row-within-group 0..3

    // runtime DPP-direction probe: need "lane h gets lane h-1 (wrap)".
    const int dprobe = __builtin_amdgcn_update_dpp(l, l, 0x121, 0xF, 0xF, false);
    const bool fwd = (__shfl(dprobe, 1, 64) == (int)0);  // ror:1 == get-left?

    const long long rowBase = (long long)blockIdx.x * 128 + wv * 16 + r;
    const float4* __restrict__ x4 = (const float4*)x;

    float acc = 0.f;
    if (fwd) {
#pragma unroll 1
        for (int g = 0; g < 4; ++g)
            acc += do_row<0x121>(x4 + (rowBase + g * 4) * 250, l);
    } else {
#pragma unroll 1
        for (int g = 0; g < 4; ++g)
            acc += do_row<0x12F>(x4 + (rowBase + g * 4) * 250, l);
    }

    // acc uniform within each 16-lane group; one rep per group, sum the wave
    float contrib = ((l & 15) == 0) ? acc : 0.f;
    contrib += __shfl_xor(contrib, 16, 64);
    contrib += __shfl_xor(contrib, 32, 64);
    if (l == 0) wsum[wv] = contrib;
    __syncthreads();

    if (t == 0) {
        float s = 0.f;
#pragma unroll
        for (int i = 0; i < 8; ++i) s += wsum[i];
        out[blockIdx.x] = s * (1.0f / 6144.0f);  // / (W=4 * K=12 * F=128)
    }
}

extern "C" void kernel_launch(void* const* d_in, const int* in_sizes, int n_in,
                              void* d_out, int out_size, void* d_ws, size_t ws_size,
                              hipStream_t stream) {
    const float* x = (const float*)d_in[0];
    float* out = (float*)d_out;
    const long long total = (long long)in_sizes[0];  // 16*128*128*1000
    const int rows = (int)(total / 1000);            // 262144
    const int blocks = rows / 128;                   // 2048 == out_size
    hipLaunchKernelGGL(ssrp_hex_kernel, dim3(blocks), dim3(512), 0, stream, x, out);
}